// Round 14
// baseline (9669.264 us; speedup 1.0000x reference)
//
#include <hip/hip_runtime.h>

#define SEQL   512
#define HID    2048
#define NCLS   10

typedef _Float16 f16x8 __attribute__((ext_vector_type(8)));
typedef float    f32x4 __attribute__((ext_vector_type(4)));

__device__ __forceinline__ float fast_tanh(float v) {
    float e = __expf(2.0f * v);
    return 1.0f - 2.0f / (e + 1.0f);
}

// Pack whh (fp32 row-major [col][k]) into fp16 MFMA fragments, two regions:
//   R [0,4MiB):  reg-pinned ksts 0..31:  frag(m,j,f,ln), col=m*64+j*16+(ln&15),
//                k0 = f*32 + (ln>>4)*8
//   P [4MiB,8MiB): LDS-pinned ksts 32..63: same but k0 = (f+32)*32 + (ln>>4)*8
__global__ void pack_w_kernel(const float* __restrict__ w, _Float16* __restrict__ o) {
    const int fid = blockIdx.x * 256 + threadIdx.x;   // 0..524287
    const int q   = fid & 262143;
    const int m  = q >> 13;
    const int r13 = q & 8191;
    const int j  = r13 >> 11;
    const int f  = (r13 >> 6) & 31;
    const int ln = r13 & 63;
    const int col = m * 64 + j * 16 + (ln & 15);
    const int k0  = ((fid < 262144 ? 0 : 32) + f) * 32 + (ln >> 4) * 8;
    const float* src = w + (size_t)col * HID + k0;
    f16x8 v;
    #pragma unroll
    for (int i = 0; i < 8; ++i) v[i] = (_Float16)src[i];
    *(f16x8*)(o + (size_t)fid * 8) = v;
}

__global__ void __launch_bounds__(512, 2)
rnn_main(const float* __restrict__ x, const float* __restrict__ whx,
         const _Float16* __restrict__ Wp, const float* __restrict__ bh,
         const float* __restrict__ wph, const float* __restrict__ bp,
         _Float16* __restrict__ h0, _Float16* __restrict__ h1,
         unsigned* __restrict__ ctr, float* __restrict__ out)
{
    // 128 KiB: LDS-pinned B ksts 32..63, frag-major: slot = jt*2048 + f*64 + lane
    __shared__ uint4 ldsB[8192];
    __shared__ unsigned s_mslot;

    const int tid = threadIdx.x;

    // physical XCD id -> group; member slot via allocator (32 WGs/XCD: 1 WG/CU,
    // forced by the 128 KiB LDS footprint)
    int xcc;
    asm volatile("s_getreg_b32 %0, hwreg(HW_REG_XCC_ID)" : "=s"(xcc));
    const int g = xcc & 7;
    unsigned* alloc = ctr + g * 64;
    unsigned* flgA  = ctr + 512 + g * 1024;           // 32 member flags, 128B stride
    unsigned* flgB  = ctr + 512 + 8192 + g * 1024;    // sub-batch B flags
    if (tid == 0)
        s_mslot = __hip_atomic_fetch_add(alloc, 1u, __ATOMIC_RELAXED, __HIP_MEMORY_SCOPE_WORKGROUP);
    __syncthreads();
    const int m = (int)s_mslot;              // 0..31
    const int rowbase = g * 32;              // rows [rowbase,+16)=A, [+16,+32)=B
    const int colbase = m * 64;

    const int lane = tid & 63;
    const int wv   = tid >> 6;               // wave 0..7
    const int jt   = wv & 3;                 // col-tile (16 cols, full K)
    const int half = wv >> 2;                // 0: rows 0..15 (A), 1: rows 16..31 (B)

    const uint4* P4 = (const uint4*)Wp;

    // ---- stage LDS-pinned B (ksts 32..63, all 4 col-tiles) ----
    for (int s5 = tid; s5 < 8192; s5 += 512)
        ldsB[s5] = P4[262144 + m * 8192 + s5];

    // ---- step 0: h = tanh(x[:,0]*whx + bh) for all 32 rows ----
    for (int i = tid; i < 32 * 64; i += 512) {
        const int r = i >> 6, c = i & 63;
        const int b = rowbase + r, jj = colbase + c;
        h0[(size_t)b * HID + jj] = (_Float16)fast_tanh(x[(size_t)b * SEQL] * whx[jj] + bh[jj]);
    }

    // ---- pin this wave's reg-B (its col-tile, ksts 0..31): 128 VGPR ----
    const uint4* R4 = P4 + m * 8192 + jt * 2048 + lane;
    f16x8 bReg[32];
    #pragma unroll
    for (int f = 0; f < 32; ++f) bReg[f] = *(const f16x8*)&R4[f * 64];

    // per-wave constants
    const int ecol = colbase + jt * 16 + (lane & 15);   // C/D col = lane&15
    const float wxc = whx[ecol], bbc = bh[ecol];
    const int erow = rowbase + half * 16 + (lane >> 4) * 4;
    // A-operand: row = rowbase + half*16 + (lane&15); kst f -> + f*32 + (lane>>4)*8
    const size_t aoff = (size_t)(rowbase + half * 16 + (lane & 15)) * HID + (lane >> 4) * 8;
    const uint4* bl = &ldsB[jt * 2048 + lane];
    unsigned* myflg = (half ? flgB : flgA) + m * 32;
    const unsigned* pollp = (half ? flgB : flgA) + (lane & 31) * 32;

    // prologue arrive: drain step-0 stores + ldsB staging, post both flag sets
    __syncthreads();
    if (tid == 0) {
        __hip_atomic_fetch_add(flgA + m * 32, 4u, __ATOMIC_RELAXED, __HIP_MEMORY_SCOPE_WORKGROUP);
        __hip_atomic_fetch_add(flgB + m * 32, 4u, __ATOMIC_RELAXED, __HIP_MEMORY_SCOPE_WORKGROUP);
    }

    // ===== per-wave independent pipeline: no intra-CU sync in the loop =====
    for (int t = 1; t < SEQL; ++t) {
        const _Float16* hs = (t & 1) ? h0 : h1;
        _Float16*       hd = (t & 1) ? h1 : h0;
        const unsigned tgt = 4u * (unsigned)t;

        // keep reg-pinned B materialized (stop reload/sinking)
        #pragma unroll
        for (int f = 0; f < 32; ++f) asm volatile("" : "+v"(bReg[f]));

        // epilogue x-values: stale-safe input, issue before the poll
        float xv[4];
        #pragma unroll
        for (int r = 0; r < 4; ++r)
            xv[r] = x[(size_t)(erow + r) * SEQL + t];

        // poll own half's 32 member flags (agent scope = L1-bypass, local L2)
        {
            unsigned v;
            do {
                v = __hip_atomic_load(pollp, __ATOMIC_RELAXED, __HIP_MEMORY_SCOPE_AGENT);
            } while (!__all((int)(v >= tgt)));
        }
        asm volatile("buffer_inv sc0" ::: "memory");   // this CU's L1 -> fresh h via L2

        const _Float16* ap = hs + aoff;
        f32x4 acc0 = {0.f,0.f,0.f,0.f}, acc1 = acc0;

        // 64 k-steps in 8 chunks of 8; av[8] loads lead each chunk's MFMAs
        #pragma unroll
        for (int c = 0; c < 8; ++c) {
            f16x8 av[8];
            #pragma unroll
            for (int u = 0; u < 8; ++u)
                av[u] = *(const f16x8*)(ap + (c * 8 + u) * 32);
            #pragma unroll
            for (int u = 0; u < 8; ++u) {
                const int f = c * 8 + u;
                const f16x8 b = (f < 32) ? bReg[f] : *(const f16x8*)&bl[(f - 32) * 64];
                if (u & 1) acc1 = __builtin_amdgcn_mfma_f32_16x16x32_f16(av[u], b, acc1, 0, 0, 0);
                else       acc0 = __builtin_amdgcn_mfma_f32_16x16x32_f16(av[u], b, acc0, 0, 0, 0);
            }
        }

        // epilogue: own output tile only — no reduce, no syncthreads
        const f32x4 s = acc0 + acc1;
        #pragma unroll
        for (int r = 0; r < 4; ++r) {
            const int br = erow + r;
            hd[(size_t)br * HID + ecol] =
                (_Float16)fast_tanh(s[r] + xv[r] * wxc + bbc);
        }
        asm volatile("s_waitcnt vmcnt(0)" ::: "memory");   // wave's stores at L2
        if (lane == 0)
            __hip_atomic_fetch_add(myflg, 1u, __ATOMIC_RELAXED, __HIP_MEMORY_SCOPE_WORKGROUP);
    }

    // final release: both halves' t=511 stores visible, then L1 inv
    {
        const unsigned tgt = 4u * (unsigned)SEQL;
        const unsigned* pA = flgA + (lane & 31) * 32;
        const unsigned* pB = flgB + (lane & 31) * 32;
        unsigned v;
        do {
            v = __hip_atomic_load(pA, __ATOMIC_RELAXED, __HIP_MEMORY_SCOPE_AGENT);
        } while (!__all((int)(v >= tgt)));
        do {
            v = __hip_atomic_load(pB, __ATOMIC_RELAXED, __HIP_MEMORY_SCOPE_AGENT);
        } while (!__all((int)(v >= tgt)));
    }
    asm volatile("buffer_inv sc0" ::: "memory");

    // ---- projection: p = h_last @ wph.T + bp (member m -> row rowbase+m) ----
    const int brow = rowbase + m;
    const _Float16* hp = h1 + (size_t)brow * HID + lane * 32;
    for (int c = wv; c < NCLS; c += 8) {
        const float* wp = wph + (size_t)c * HID + lane * 32;
        float psum = 0.f;
        #pragma unroll
        for (int i = 0; i < 32; ++i) psum += (float)hp[i] * wp[i];
        #pragma unroll
        for (int off = 32; off >= 1; off >>= 1) psum += __shfl_xor(psum, off, 64);
        if (lane == 0) out[brow * NCLS + c] = psum + bp[c];
    }
}

extern "C" void kernel_launch(void* const* d_in, const int* in_sizes, int n_in,
                              void* d_out, int out_size, void* d_ws, size_t ws_size,
                              hipStream_t stream) {
    const float* x   = (const float*)d_in[0];
    const float* whx = (const float*)d_in[1];
    const float* whh = (const float*)d_in[2];
    const float* bh  = (const float*)d_in[3];
    const float* wph = (const float*)d_in[4];
    const float* bp  = (const float*)d_in[5];
    float* out = (float*)d_out;

    char* ws = (char*)d_ws;
    _Float16* Wp  = (_Float16*)ws;                         // 8 MiB packed whh fp16 (R + P)
    _Float16* h0  = (_Float16*)(ws + (size_t)(8u << 20));  // 1 MiB  h buffer A
    _Float16* h1  = (_Float16*)(ws + (size_t)(9u << 20));  // 1 MiB  h buffer B
    unsigned* ctr = (unsigned*)(ws + (size_t)(10u << 20)); // 68 KiB alloc + 2x flags

    hipMemsetAsync(ctr, 0, (512 + 2 * 8 * 1024) * sizeof(unsigned), stream);
    pack_w_kernel<<<dim3(2048), dim3(256), 0, stream>>>(whh, Wp);

    void* args[] = { (void*)&x, (void*)&whx, (void*)&Wp, (void*)&bh, (void*)&wph,
                     (void*)&bp, (void*)&h0, (void*)&h1, (void*)&ctr, (void*)&out };
    hipLaunchCooperativeKernel((const void*)rnn_main, dim3(256), dim3(512),
                               args, 0, stream);
}

// Round 15
// 4511.389 us; speedup vs baseline: 2.1433x; 2.1433x over previous
//
#include <hip/hip_runtime.h>

#define SEQL   512
#define HID    2048
#define NCLS   10

typedef _Float16 f16x8 __attribute__((ext_vector_type(8)));
typedef float    f32x4 __attribute__((ext_vector_type(4)));

__device__ __forceinline__ float fast_tanh(float v) {
    float e = __expf(2.0f * v);
    return 1.0f - 2.0f / (e + 1.0f);
}

// Pack whh (fp32 row-major [col][k]) into fp16 MFMA fragments, member-major:
// member m owns 256 frags (64 cols x 64 ksts); frag = 16 cols x 32 k = 1KB.
//   local 0..95   (LDS):  tj in {0,1}, q 0..3, i 0..11 -> tile tj, kst q*16+i
//   local 96..255 (regs): wave w=(cbb,kq), f 0..19:
//       f<4  -> tile cbb,   kst kq*16+12+f   (the 4 ksts LDS doesn't hold)
//       f>=4 -> tile 2+cbb, kst kq*16+(f-4)  (high tiles fully in regs)
__global__ void pack_w_kernel(const float* __restrict__ w, _Float16* __restrict__ o) {
    const int fid = blockIdx.x * 256 + threadIdx.x;   // 0..524287
    const int ln   = fid & 63;
    const int frag = fid >> 6;
    const int m     = frag >> 8;
    const int local = frag & 255;
    int tile, kst;
    if (local < 96) {
        const int tj = local / 48, r = local % 48;
        tile = tj;
        kst  = (r / 12) * 16 + (r % 12);
    } else {
        const int l2 = local - 96;
        const int wv = l2 / 20, f = l2 % 20;
        const int cbb = wv & 1, kq = wv >> 1;
        if (f < 4) { tile = cbb;     kst = kq * 16 + 12 + f; }
        else       { tile = 2 + cbb; kst = kq * 16 + (f - 4); }
    }
    const int col = m * 64 + tile * 16 + (ln & 15);
    const int k0  = kst * 32 + (ln >> 4) * 8;
    const float* src = w + (size_t)col * HID + k0;
    f16x8 v;
    #pragma unroll
    for (int i = 0; i < 8; ++i) v[i] = (_Float16)src[i];
    *(f16x8*)(o + (size_t)fid * 8) = v;
}

__global__ void __launch_bounds__(512, 2)
rnn_main(const float* __restrict__ x, const float* __restrict__ whx,
         const _Float16* __restrict__ Wp, const float* __restrict__ bh,
         const float* __restrict__ wph, const float* __restrict__ bp,
         _Float16* __restrict__ h0, _Float16* __restrict__ h1,
         unsigned* __restrict__ ctr, float* __restrict__ out)
{
    // 96 KiB pinned W (LDS frags): slot = (tj*48 + q*12 + i)*64 + lane
    __shared__ uint4 ldsW[6144];
    // 2 x 16 KiB partial buffers (A/B halves): slot = (tile*4 + kq)*64 + lane
    __shared__ f32x4 ldsPA[16 * 64];
    __shared__ f32x4 ldsPB[16 * 64];
    __shared__ unsigned s_mslot;

    const int tid = threadIdx.x;

    // physical XCD id -> group; member slot via allocator (32 WGs/XCD: 1 WG/CU)
    int xcc;
    asm volatile("s_getreg_b32 %0, hwreg(HW_REG_XCC_ID)" : "=s"(xcc));
    const int g = xcc & 7;
    unsigned* alloc = ctr + g * 64;
    unsigned* flgA  = ctr + 512 + g * 1024;           // 32 member flags, 128B stride
    unsigned* flgB  = ctr + 512 + 8192 + g * 1024;    // half-B flags
    if (tid == 0)
        s_mslot = __hip_atomic_fetch_add(alloc, 1u, __ATOMIC_RELAXED, __HIP_MEMORY_SCOPE_WORKGROUP);
    __syncthreads();
    const int m = (int)s_mslot;              // 0..31
    const int rowbase = g * 32;              // rows [rowbase,+16)=A, [+16,+32)=B
    const int colbase = m * 64;

    const int lane = tid & 63;
    const int wv   = tid >> 6;               // wave 0..7
    const int cbb  = wv & 1;                 // low-tile index (tiles cbb and 2+cbb)
    const int kq   = wv >> 1;                // kst quarter 0..3

    const uint4* P4 = (const uint4*)Wp;

    // ---- stage LDS W frags (member's first 96 frags, contiguous) ----
    for (int s5 = tid; s5 < 6144; s5 += 512)
        ldsW[s5] = P4[m * 16384 + s5];

    // ---- step 0: h = tanh(x[:,0]*whx + bh) for all 32 rows ----
    for (int i = tid; i < 32 * 64; i += 512) {
        const int r = i >> 6, c = i & 63;
        const int b = rowbase + r, jj = colbase + c;
        h0[(size_t)b * HID + jj] = (_Float16)fast_tanh(x[(size_t)b * SEQL] * whx[jj] + bh[jj]);
    }

    // ---- pin this wave's 20 reg frags (80 VGPR / AGPR) ----
    const uint4* R4 = P4 + m * 16384 + (96 + wv * 20) * 64 + lane;
    f16x8 bReg[20];
    #pragma unroll
    for (int f = 0; f < 20; ++f) bReg[f] = *(const f16x8*)&R4[f * 64];

    // reducer job: wave wv -> half (wv>>2 ? B : A), tile wv&3
    const int rtile = wv & 3;
    const int rhalf = wv >> 2;
    const int ecol = colbase + rtile * 16 + (lane & 15);
    const float wxc = whx[ecol], bbc = bh[ecol];
    const int erow = rowbase + rhalf * 16 + (lane >> 4) * 4;
    f32x4* ldsPR = rhalf ? ldsPB : ldsPA;

    // A-operand geometry: row = rowbase(+16) + (lane&15), k = kq*512 + i*32 + (lane>>4)*8
    const size_t aoffA = (size_t)(rowbase + (lane & 15)) * HID + kq * 512 + (lane >> 4) * 8;
    const size_t aoffB = aoffA + (size_t)16 * HID;
    const uint4* blw = &ldsW[(cbb * 48 + kq * 12) * 64 + lane];
    unsigned* myflg = (rhalf ? flgB : flgA) + m * 32;
    const unsigned* pollA = flgA + (lane & 31) * 32;
    const unsigned* pollB = flgB + (lane & 31) * 32;

    // prologue arrive: drain step-0 stores + staging, post both flag sets (+4)
    __syncthreads();
    if (tid == 0) {
        __hip_atomic_fetch_add(flgA + m * 32, 4u, __ATOMIC_RELAXED, __HIP_MEMORY_SCOPE_WORKGROUP);
        __hip_atomic_fetch_add(flgB + m * 32, 4u, __ATOMIC_RELAXED, __HIP_MEMORY_SCOPE_WORKGROUP);
    }

    for (int t = 1; t < SEQL; ++t) {
        const _Float16* hs = (t & 1) ? h0 : h1;
        _Float16*       hd = (t & 1) ? h1 : h0;
        const unsigned tgt = 4u * (unsigned)t;

        // keep reg-pinned frags materialized
        #pragma unroll
        for (int f = 0; f < 20; ++f) asm volatile("" : "+v"(bReg[f]));

        // reducer's x-values: stale-safe input, issue before polls
        float xv[4];
        #pragma unroll
        for (int r = 0; r < 4; ++r)
            xv[r] = x[(size_t)(erow + r) * SEQL + t];

        // ---- half A: poll, inv, compute partials (tiles cbb & 2+cbb) ----
        {
            unsigned v;
            do {
                v = __hip_atomic_load(pollA, __ATOMIC_RELAXED, __HIP_MEMORY_SCOPE_AGENT);
            } while (!__all((int)(v >= tgt)));
        }
        asm volatile("buffer_inv sc0" ::: "memory");

        f32x4 aLo = {0.f,0.f,0.f,0.f}, aHi = aLo;
        {
            const _Float16* ap = hs + aoffA;
            #pragma unroll
            for (int i = 0; i < 16; ++i) {
                const f16x8 a  = *(const f16x8*)(ap + i * 32);
                const f16x8 bL = (i < 12) ? *(const f16x8*)&blw[i * 64] : bReg[i - 12];
                const f16x8 bH = bReg[4 + i];
                aLo = __builtin_amdgcn_mfma_f32_16x16x32_f16(a, bL, aLo, 0, 0, 0);
                aHi = __builtin_amdgcn_mfma_f32_16x16x32_f16(a, bH, aHi, 0, 0, 0);
            }
        }
        ldsPA[(cbb * 4 + kq) * 64 + lane]       = aLo;
        ldsPA[((2 + cbb) * 4 + kq) * 64 + lane] = aHi;

        // ---- half B: poll, inv, compute partials ----
        {
            unsigned v;
            do {
                v = __hip_atomic_load(pollB, __ATOMIC_RELAXED, __HIP_MEMORY_SCOPE_AGENT);
            } while (!__all((int)(v >= tgt)));
        }
        asm volatile("buffer_inv sc0" ::: "memory");

        f32x4 bLo = {0.f,0.f,0.f,0.f}, bHi = bLo;
        {
            const _Float16* ap = hs + aoffB;
            #pragma unroll
            for (int i = 0; i < 16; ++i) {
                const f16x8 a  = *(const f16x8*)(ap + i * 32);
                const f16x8 bL = (i < 12) ? *(const f16x8*)&blw[i * 64] : bReg[i - 12];
                const f16x8 bH = bReg[4 + i];
                bLo = __builtin_amdgcn_mfma_f32_16x16x32_f16(a, bL, bLo, 0, 0, 0);
                bHi = __builtin_amdgcn_mfma_f32_16x16x32_f16(a, bH, bHi, 0, 0, 0);
            }
        }
        ldsPB[(cbb * 4 + kq) * 64 + lane]       = bLo;
        ldsPB[((2 + cbb) * 4 + kq) * 64 + lane] = bHi;

        __syncthreads();   // all partials visible

        // ---- reduce own (half, tile): sum 4 kq partials, epilogue, store, flag ----
        {
            const f32x4 s = ldsPR[(rtile * 4 + 0) * 64 + lane]
                          + ldsPR[(rtile * 4 + 1) * 64 + lane]
                          + ldsPR[(rtile * 4 + 2) * 64 + lane]
                          + ldsPR[(rtile * 4 + 3) * 64 + lane];
            #pragma unroll
            for (int r = 0; r < 4; ++r) {
                const int br = erow + r;
                hd[(size_t)br * HID + ecol] =
                    (_Float16)fast_tanh(s[r] + xv[r] * wxc + bbc);
            }
            asm volatile("s_waitcnt vmcnt(0)" ::: "memory");   // stores at L2
            if (lane == 0)
                __hip_atomic_fetch_add(myflg, 1u, __ATOMIC_RELAXED, __HIP_MEMORY_SCOPE_WORKGROUP);
        }

        __syncthreads();   // protect ldsP from next step's writes
    }

    // final release: both halves' t=511 stores visible, then L1 inv
    {
        const unsigned tgt = 4u * (unsigned)SEQL;
        unsigned v;
        do {
            v = __hip_atomic_load(pollA, __ATOMIC_RELAXED, __HIP_MEMORY_SCOPE_AGENT);
        } while (!__all((int)(v >= tgt)));
        do {
            v = __hip_atomic_load(pollB, __ATOMIC_RELAXED, __HIP_MEMORY_SCOPE_AGENT);
        } while (!__all((int)(v >= tgt)));
    }
    asm volatile("buffer_inv sc0" ::: "memory");

    // ---- projection: p = h_last @ wph.T + bp (member m -> row rowbase+m) ----
    const int brow = rowbase + m;
    const _Float16* hp = h1 + (size_t)brow * HID + lane * 32;
    for (int c = wv; c < NCLS; c += 8) {
        const float* wp = wph + (size_t)c * HID + lane * 32;
        float psum = 0.f;
        #pragma unroll
        for (int i = 0; i < 32; ++i) psum += (float)hp[i] * wp[i];
        #pragma unroll
        for (int off = 32; off >= 1; off >>= 1) psum += __shfl_xor(psum, off, 64);
        if (lane == 0) out[brow * NCLS + c] = psum + bp[c];
    }
}

extern "C" void kernel_launch(void* const* d_in, const int* in_sizes, int n_in,
                              void* d_out, int out_size, void* d_ws, size_t ws_size,
                              hipStream_t stream) {
    const float* x   = (const float*)d_in[0];
    const float* whx = (const float*)d_in[1];
    const float* whh = (const float*)d_in[2];
    const float* bh  = (const float*)d_in[3];
    const float* wph = (const float*)d_in[4];
    const float* bp  = (const float*)d_in[5];
    float* out = (float*)d_out;

    char* ws = (char*)d_ws;
    _Float16* Wp  = (_Float16*)ws;                         // 8 MiB packed whh fp16
    _Float16* h0  = (_Float16*)(ws + (size_t)(8u << 20));  // 1 MiB  h buffer A
    _Float16* h1  = (_Float16*)(ws + (size_t)(9u << 20));  // 1 MiB  h buffer B
    unsigned* ctr = (unsigned*)(ws + (size_t)(10u << 20)); // 68 KiB alloc + 2x flags

    hipMemsetAsync(ctr, 0, (512 + 2 * 8 * 1024) * sizeof(unsigned), stream);
    pack_w_kernel<<<dim3(2048), dim3(256), 0, stream>>>(whh, Wp);

    void* args[] = { (void*)&x, (void*)&whx, (void*)&Wp, (void*)&bh, (void*)&wph,
                     (void*)&bp, (void*)&h0, (void*)&h1, (void*)&ctr, (void*)&out };
    hipLaunchCooperativeKernel((const void*)rnn_main, dim3(256), dim3(512),
                               args, 0, stream);
}